// Round 10
// baseline (304.338 us; speedup 1.0000x reference)
//
#include <hip/hip_runtime.h>

typedef __attribute__((ext_vector_type(8))) short bfrag8;          // 8 bf16 in 4 VGPRs
typedef __attribute__((ext_vector_type(4))) float facc4;           // 4 fp32 acc
typedef __attribute__((ext_vector_type(8))) unsigned short u16x8;  // 16B lane load

#define CROWS  256    // rows per coarse bucket (rl fits 8 bits)
#define NCBMAX 512    // max coarse buckets (N <= 131072; col fits 17 bits)
#define CAP    8192   // bkt region capacity per bucket (~2x expected 4081)
#define CHUNK  2048   // edges per k_part block (782 blocks -> ~3/CU, balanced)
#define SLACK  1800   // per-bucket cidx padding slack (256 rows * 7 + align)

static __device__ __forceinline__ float bf2f(ushort u) {
    union { unsigned int i; float f; } x;
    x.i = ((unsigned int)u) << 16;
    return x.f;
}
static __device__ __forceinline__ ushort f2bf(float f) {
    union { float f; unsigned int i; } x;
    x.f = f;
    unsigned int r = x.i + 0x7FFFu + ((x.i >> 16) & 1u);   // RNE
    return (ushort)(r >> 16);
}

// ---------------- preprocessing: 2-phase partition, no global random atomics ----

// init bucket cursors + zero the sentinel row T2[N] (gathers of padding hit it)
__global__ void k_cinit(int* __restrict__ ccur, int ncb, ushort* __restrict__ t, int N) {
    int b = blockIdx.x * blockDim.x + threadIdx.x;
    if (b < ncb) ccur[b] = b * CAP;
    if (blockIdx.x == 0 && threadIdx.x < 64) t[(size_t)N * 64 + threadIdx.x] = 0;
}

__global__ void k_part(const int* __restrict__ row, const int* __restrict__ col, int E,
                       int* __restrict__ ccur, int* __restrict__ bkt, int ncb) {
    __shared__ int recs[CHUNK];          // packed (rl<<17|col)
    __shared__ unsigned short cbl[CHUNK];
    __shared__ int hist[NCBMAX], lbase[NCBMAX], loff[NCBMAX];
    int tid = threadIdx.x;
    int chunk0 = blockIdx.x * CHUNK;
    for (int i = tid; i < ncb; i += blockDim.x) hist[i] = 0;
    __syncthreads();
    for (int j = tid; j < CHUNK; j += blockDim.x) {
        int e = chunk0 + j;
        if (e < E) {
            int r = row[e];
            int cb = r >> 8;
            recs[j] = ((r & (CROWS - 1)) << 17) | col[e];
            cbl[j] = (unsigned short)cb;
            atomicAdd(&hist[cb], 1);
        } else cbl[j] = 0xFFFF;
    }
    __syncthreads();
    for (int i = tid; i < ncb; i += blockDim.x) {
        int h = hist[i];
        lbase[i] = h ? atomicAdd(&ccur[i], h) : 0;
        loff[i] = 0;
    }
    __syncthreads();
    for (int j = tid; j < CHUNK; j += blockDim.x) {
        unsigned short cb = cbl[j];
        if (cb != 0xFFFF) {
            int p = lbase[cb] + atomicAdd(&loff[cb], 1);
            if (p < (cb + 1) * CAP) bkt[p] = recs[j];   // overflow guard (never hits)
        }
    }
}

__global__ void k_scan(const int* __restrict__ ccur, int* __restrict__ cbase, int ncb) {
    __shared__ int tmp[NCBMAX];
    int tid = threadIdx.x;
    int v = (tid < ncb) ? min(ccur[tid] - tid * CAP, CAP) : 0;
    tmp[tid] = v;
    __syncthreads();
    #pragma unroll
    for (int off = 1; off < NCBMAX; off <<= 1) {
        int t = (tid >= off) ? tmp[tid - off] : 0;
        __syncthreads();
        tmp[tid] += t;
        __syncthreads();
    }
    if (tid < ncb) cbase[tid] = tmp[tid] - v;   // exclusive
    if (tid == ncb - 1) cbase[ncb] = tmp[tid];
}

// per bucket: row hist -> deg/dinv, padded-window scan -> rptr (8-aligned),
// LDS-cursor placement, sentinel fill. Zero global atomics.
__global__ void k_build(const int* __restrict__ bkt, const int* __restrict__ ccur,
                        const int* __restrict__ cbase,
                        int* __restrict__ rptr, int* __restrict__ deg,
                        float* __restrict__ dinv, int* __restrict__ cidx, int N) {
    __shared__ int hist[CROWS], wstart[CROWS], cur[CROWS], psum[CROWS];
    int tid = threadIdx.x;
    int b = blockIdx.x;
    int lo = b * CROWS;
    int nr = min(CROWS, N - lo);
    int in0 = b * CAP;
    int cntE = min(ccur[b] - in0, CAP);
    int out0 = ((cbase[b] + 7) & ~7) + b * SLACK;   // 32B-aligned bucket base

    hist[tid] = 0;
    __syncthreads();
    for (int i = tid; i < cntE; i += blockDim.x)
        atomicAdd(&hist[bkt[in0 + i] >> 17], 1);
    __syncthreads();
    int d = hist[tid];
    int ep = (d + 7) & ~7;                  // padded row length (multiple of 8)
    psum[tid] = ep;
    __syncthreads();
    #pragma unroll
    for (int off = 1; off < CROWS; off <<= 1) {
        int t = (tid >= off) ? psum[tid - off] : 0;
        __syncthreads();
        psum[tid] += t;
        __syncthreads();
    }
    int ws = out0 + psum[tid] - ep;
    wstart[tid] = ws;
    cur[tid] = ws;
    if (tid < nr) {
        rptr[lo + tid] = ws;
        deg[lo + tid] = d;
        dinv[lo + tid] = rsqrtf((float)(d + 1));   // +1 self-loop
    }
    __syncthreads();
    for (int i = tid; i < cntE; i += blockDim.x) {
        int v = bkt[in0 + i];
        int p = atomicAdd(&cur[v >> 17], 1);
        cidx[p] = v & 0x1FFFF;
    }
    __syncthreads();
    if (tid < nr)
        for (int j = d; j < ep; j++) cidx[wstart[tid] + j] = N;   // sentinels
}

// ---------------- MFMA GEMM: T2[N,64] = dinv[n] * (H[N,64] @ W[64,64]) ----------------
template <bool FP32IN>
__global__ void k_gemm(const void* __restrict__ Hv, const float* __restrict__ W,
                       const float* __restrict__ dinv,
                       ushort* __restrict__ T, int ntiles, int N) {
    int lane = threadIdx.x & 63;
    int wid = (blockIdx.x * blockDim.x + threadIdx.x) >> 6;
    int nw = (gridDim.x * blockDim.x) >> 6;
    int m = lane & 15, quad = lane >> 4;

    bfrag8 bf[2][4];   // all of W in B-frags, loaded once
    #pragma unroll
    for (int s = 0; s < 2; s++)
        #pragma unroll
        for (int c = 0; c < 4; c++) {
            bfrag8 f;
            #pragma unroll
            for (int j = 0; j < 8; j++) {
                int k = 32 * s + quad * 8 + j;
                f[j] = (short)f2bf(W[k * 64 + 16 * c + m]);
            }
            bf[s][c] = f;
        }

    for (int t = wid; t < ntiles; t += nw) {
        int nodeA = t * 16 + m;
        if (nodeA >= N) nodeA = N - 1;
        bfrag8 a0, a1;
        if (FP32IN) {
            const float* arow = (const float*)Hv + (size_t)nodeA * 64;
            #pragma unroll
            for (int s = 0; s < 2; s++) {
                float4 u0 = *(const float4*)(arow + s * 32 + quad * 8);
                float4 u1 = *(const float4*)(arow + s * 32 + quad * 8 + 4);
                bfrag8 f;
                f[0] = (short)f2bf(u0.x); f[1] = (short)f2bf(u0.y);
                f[2] = (short)f2bf(u0.z); f[3] = (short)f2bf(u0.w);
                f[4] = (short)f2bf(u1.x); f[5] = (short)f2bf(u1.y);
                f[6] = (short)f2bf(u1.z); f[7] = (short)f2bf(u1.w);
                if (s == 0) a0 = f; else a1 = f;
            }
        } else {
            const ushort* arow = (const ushort*)Hv + (size_t)nodeA * 64;
            a0 = *(const bfrag8*)(arow + quad * 8);
            a1 = *(const bfrag8*)(arow + 32 + quad * 8);
        }
        facc4 acc[4];
        #pragma unroll
        for (int c = 0; c < 4; c++) { acc[c][0]=0.f; acc[c][1]=0.f; acc[c][2]=0.f; acc[c][3]=0.f; }
        #pragma unroll
        for (int c = 0; c < 4; c++) {
            acc[c] = __builtin_amdgcn_mfma_f32_16x16x32_bf16(a0, bf[0][c], acc[c], 0, 0, 0);
            acc[c] = __builtin_amdgcn_mfma_f32_16x16x32_bf16(a1, bf[1][c], acc[c], 0, 0, 0);
        }
        #pragma unroll
        for (int c = 0; c < 4; c++)
            #pragma unroll
            for (int r = 0; r < 4; r++) {
                int node = t * 16 + quad * 4 + r;
                if (node < N)
                    T[(size_t)node * 64 + c * 16 + m] = f2bf(dinv[node] * acc[c][r]);
            }
    }
}

// ---------------- fused propagate + bias + BN + ReLU ----------------
// T2 pre-scaled by dinv[c]; rows padded to x8 with sentinel->zero-row:
// mask-free inner loop, 8 edges (2 int4 + 8 u16x8 loads) in flight per step.
__global__ void k_agg(const ushort* __restrict__ T2, const int* __restrict__ rptr,
                      const int* __restrict__ deg, const float* __restrict__ dinv,
                      const int* __restrict__ cidx,
                      const float* __restrict__ bias, const float* __restrict__ g,
                      const float* __restrict__ be, const float* __restrict__ mm,
                      const float* __restrict__ vv, int do_bn,
                      float* __restrict__ outf, ushort* __restrict__ outb, int N) {
    int lane = threadIdx.x & 63;
    int wid = (blockIdx.x * blockDim.x + threadIdx.x) >> 6;
    int nw = (gridDim.x * blockDim.x) >> 6;
    int grp = lane >> 3;      // which of 8 rows
    int s = lane & 7;         // channel slice: s*8 .. s*8+7

    float bb[8], sc[8], sh[8];
    #pragma unroll
    for (int k = 0; k < 8; k++) { bb[k] = bias[s * 8 + k]; sc[k] = 1.f; sh[k] = 0.f; }
    if (do_bn) {
        #pragma unroll
        for (int k = 0; k < 8; k++) {
            sc[k] = g[s * 8 + k] * rsqrtf(vv[s * 8 + k] + 1e-5f);
            sh[k] = be[s * 8 + k] - mm[s * 8 + k] * sc[k];
        }
    }

    int noct = (N + 7) >> 3;
    for (int q = wid; q < noct; q += nw) {
        int r = q * 8 + grp;
        bool rv = (r < N);
        int start = rv ? rptr[r] : 0;
        int ep = rv ? ((deg[r] + 7) & ~7) : 0;
        float a[8];
        #pragma unroll
        for (int k = 0; k < 8; k++) a[k] = 0.f;
        for (int i = 0; i < ep; i += 8) {
            int4 ca = *(const int4*)(cidx + start + i);       // 2 loads = 8 edges
            int4 cb = *(const int4*)(cidx + start + i + 4);
            u16x8 t0 = *(const u16x8*)(T2 + (size_t)ca.x * 64 + s * 8);
            u16x8 t1 = *(const u16x8*)(T2 + (size_t)ca.y * 64 + s * 8);
            u16x8 t2 = *(const u16x8*)(T2 + (size_t)ca.z * 64 + s * 8);
            u16x8 t3 = *(const u16x8*)(T2 + (size_t)ca.w * 64 + s * 8);
            u16x8 t4 = *(const u16x8*)(T2 + (size_t)cb.x * 64 + s * 8);
            u16x8 t5 = *(const u16x8*)(T2 + (size_t)cb.y * 64 + s * 8);
            u16x8 t6 = *(const u16x8*)(T2 + (size_t)cb.z * 64 + s * 8);
            u16x8 t7 = *(const u16x8*)(T2 + (size_t)cb.w * 64 + s * 8);
            #pragma unroll
            for (int k = 0; k < 8; k++) {
                float p0 = (bf2f(t0[k]) + bf2f(t1[k])) + (bf2f(t2[k]) + bf2f(t3[k]));
                float p1 = (bf2f(t4[k]) + bf2f(t5[k])) + (bf2f(t6[k]) + bf2f(t7[k]));
                a[k] += p0 + p1;
            }
        }
        if (rv) {
            u16x8 sf = *(const u16x8*)(T2 + (size_t)r * 64 + s * 8);
            float dr = dinv[r];
            float v[8];
            #pragma unroll
            for (int k = 0; k < 8; k++) {
                v[k] = dr * (a[k] + bf2f(sf[k])) + bb[k];
                if (do_bn) v[k] = fmaxf(v[k] * sc[k] + sh[k], 0.f);
            }
            if (outf) {
                *(float4*)(outf + (size_t)r * 64 + s * 8) = make_float4(v[0], v[1], v[2], v[3]);
                *(float4*)(outf + (size_t)r * 64 + s * 8 + 4) = make_float4(v[4], v[5], v[6], v[7]);
            }
            if (outb) {
                u16x8 o;
                #pragma unroll
                for (int k = 0; k < 8; k++) o[k] = f2bf(v[k]);
                *(u16x8*)(outb + (size_t)r * 64 + s * 8) = o;
            }
        }
    }
}

// ---------------- launcher ----------------

extern "C" void kernel_launch(void* const* d_in, const int* in_sizes, int n_in,
                              void* d_out, int out_size, void* d_ws, size_t ws_size,
                              hipStream_t stream) {
    const float* x  = (const float*)d_in[0];
    const int*   ei = (const int*)d_in[1];
    const float *W1 = (const float*)d_in[2],  *b1 = (const float*)d_in[3];
    const float *g1 = (const float*)d_in[4],  *be1= (const float*)d_in[5];
    const float *m1 = (const float*)d_in[6],  *v1 = (const float*)d_in[7];
    const float *W2 = (const float*)d_in[8],  *b2 = (const float*)d_in[9];
    const float *g2 = (const float*)d_in[10], *be2= (const float*)d_in[11];
    const float *m2 = (const float*)d_in[12], *v2 = (const float*)d_in[13];
    const float *W3 = (const float*)d_in[14], *b3 = (const float*)d_in[15];

    int N = in_sizes[0] / 64;
    int E = in_sizes[1] / 2;
    const int* row = ei;
    const int* col = ei + E;
    int ncb = (N + CROWS - 1) / CROWS;

    char* p = (char*)d_ws;
    auto take = [&](size_t b) -> char* {
        char* q = p;
        p += (b + 255) & ~(size_t)255;
        return q;
    };
    int*    ccur  = (int*)   take((size_t)ncb * 4);
    int*    cbase = (int*)   take((size_t)(ncb + 1) * 4);
    int*    rptr  = (int*)   take((size_t)N * 4);
    int*    deg   = (int*)   take((size_t)N * 4);
    float*  dinv  = (float*) take((size_t)N * 4);
    int*    bkt   = (int*)   take((size_t)ncb * CAP * 4);
    int*    cidx  = (int*)   take((size_t)(E + ncb * SLACK + 64) * 4);
    ushort* t     = (ushort*)take((size_t)(N + 1) * 64 * 2);   // +1 sentinel row
    ushort* h     = (ushort*)take((size_t)N * 64 * 2);

    const int TB = 256;
    int nchunks = (E + CHUNK - 1) / CHUNK;
    k_cinit<<<(ncb + TB - 1) / TB, TB, 0, stream>>>(ccur, ncb, t, N);
    k_part <<<nchunks, TB, 0, stream>>>(row, col, E, ccur, bkt, ncb);
    k_scan <<<1, NCBMAX, 0, stream>>>(ccur, cbase, ncb);
    k_build<<<ncb, TB, 0, stream>>>(bkt, ccur, cbase, rptr, deg, dinv, cidx, N);

    float* outp = (float*)d_out;   // [0, N*64): embeddings fp32; [N*64, 2N*64): preds
    int ntiles = (N + 15) >> 4;
    const int GG = 1024;                       // gemm blocks
    int noct = (N + 7) >> 3;
    int GA = (noct + 3) / 4;                   // one row-octet per wave

    // layer 1 (fp32 x read directly, converted in-kernel)
    k_gemm<true> <<<GG, TB, 0, stream>>>(x, W1, dinv, t, ntiles, N);
    k_agg <<<GA, TB, 0, stream>>>(t, rptr, deg, dinv, cidx, b1, g1, be1, m1, v1, 1,
                                  (float*)nullptr, h, N);
    // layer 2 -> embeddings (fp32 to d_out) + bf16 h for layer 3
    k_gemm<false><<<GG, TB, 0, stream>>>(h, W2, dinv, t, ntiles, N);
    k_agg <<<GA, TB, 0, stream>>>(t, rptr, deg, dinv, cidx, b2, g2, be2, m2, v2, 1,
                                  outp, h, N);
    // layer 3 -> predictions
    k_gemm<false><<<GG, TB, 0, stream>>>(h, W3, dinv, t, ntiles, N);
    k_agg <<<GA, TB, 0, stream>>>(t, rptr, deg, dinv, cidx, b3, b3, b3, b3, b3, 0,
                                  outp + (size_t)N * 64, (ushort*)nullptr, N);
}